// Round 11
// baseline (160.637 us; speedup 1.0000x reference)
//
#include <hip/hip_runtime.h>

// Problem constants (B=32, T=1024, H=1024)
#define BB 32
#define TT 1024
#define HH 1024
#define MM (BB * TT)   // 32768 rows of the score GEMM

typedef __bf16 bf16x8 __attribute__((ext_vector_type(8)));
typedef float  f32x4  __attribute__((ext_vector_type(4)));

__device__ __forceinline__ void async_copy16(const void* g, void* l) {
  __builtin_amdgcn_global_load_lds(
      (const __attribute__((address_space(1))) void*)g,
      (__attribute__((address_space(3))) void*)l, 16, 0, 0);
}

__device__ __forceinline__ float fast_tanh(float x) {
  float e2 = __expf(2.f * x);                          // v_mul + v_exp
  return 1.f - 2.f * __builtin_amdgcn_rcpf(e2 + 1.f);  // saturates +/-1
}

// ---------------- K0 (mini-prep): hproj + cvt(Ua) + zero(e) ---------------
// Ua cvt keeps the verified chunk layout: chunk R: c=R&2047, t=R>>11,
// kt=t&15, rt=t>>4, u=c>>10, idx=(c>>3)&127, s=c&7, g=s^(idx&7),
// row=(idx&63)+128*((idx>>6)&1)+u*64.
// Blocks [0,128): hproj. [128,256): Ua cvt. Block 256: zero e.
__global__ __launch_bounds__(256) void mini_prep_kernel(
    const float* __restrict__ Ua, const float* __restrict__ h_t,
    const float* __restrict__ Wa, __bf16* __restrict__ uab,
    float* __restrict__ hp, float* __restrict__ e) {
  const int blk = blockIdx.x;
  const int tid = threadIdx.x;

  if (blk < 128) {
    const int b = blk >> 2;
    const int k = (blk & 3) * 256 + tid;
    __shared__ float hs[HH];
    for (int i = tid; i < HH; i += 256) hs[i] = h_t[b * HH + i];
    __syncthreads();
    const float4* w  = (const float4*)(Wa + (size_t)k * HH);
    const float4* hv = (const float4*)hs;
    float acc = 0.f;
#pragma unroll 8
    for (int i = 0; i < HH / 4; ++i) {
      float4 a = w[i];
      float4 h = hv[i];
      acc += a.x * h.x + a.y * h.y + a.z * h.z + a.w * h.w;
    }
    hp[b * HH + k] = acc;
  } else if (blk < 256) {
    int F = (blk - 128) * 256 + tid;
#pragma unroll
    for (int it = 0; it < 4; ++it, F += 32768) {
      const int c   = F & 2047;
      const int t   = F >> 11;
      const int kt  = t & 15;
      const int rt  = t >> 4;
      const int u   = c >> 10;
      const int idx = (c >> 3) & 127;
      const int s   = c & 7;
      const int g   = s ^ (idx & 7);
      const int row = (idx & 63) + ((idx >> 6) & 1) * 128 + u * 64;
      const float* sp = Ua + (((size_t)rt * 256 + row) << 10) + (kt << 6) + (g << 3);
      f32x4 a  = *(const f32x4*)sp;
      f32x4 b2 = *(const f32x4*)(sp + 4);
      bf16x8 o;
      o[0] = (__bf16)a[0];  o[1] = (__bf16)a[1];
      o[2] = (__bf16)a[2];  o[3] = (__bf16)a[3];
      o[4] = (__bf16)b2[0]; o[5] = (__bf16)b2[1];
      o[6] = (__bf16)b2[2]; o[7] = (__bf16)b2[3];
      *(bf16x8*)(uab + (size_t)F * 8) = o;
    }
  } else {
    f32x4 z = {0.f, 0.f, 0.f, 0.f};
    f32x4* ep = (f32x4*)e;
#pragma unroll
    for (int i = 0; i < 32; ++i) ep[i * 256 + tid] = z;
  }
}

// ---------------- K1 (fallback only): standalone hproj --------------------
__global__ __launch_bounds__(128) void hproj_kernel(
    const float* __restrict__ h_t, const float* __restrict__ Wa,
    float* __restrict__ hp) {
  const int k = blockIdx.x * 128 + threadIdx.x;
  const int b = blockIdx.y;
  __shared__ float hs[HH];
  for (int i = threadIdx.x; i < HH; i += 128) hs[i] = h_t[b * HH + i];
  __syncthreads();
  const float4* w  = (const float4*)(Wa + (size_t)k * HH);
  const float4* hv = (const float4*)hs;
  float acc = 0.f;
#pragma unroll 8
  for (int i = 0; i < HH / 4; ++i) {
    float4 a = w[i];
    float4 h = hv[i];
    acc += a.x * h.x + a.y * h.y + a.z * h.z + a.w * h.w;
  }
  hp[b * HH + k] = acc;
}

// ---------------- K2 (fast path): 256^2 8-phase score GEMM, fused A-cvt ---
// R11 schedule (rebalanced + distributed A-publish). Issue order per tile t:
//   ph0: ds_read B-kk0(4)+A-m0..3-kk0(4); ALOAD AY(t+1)
//   ph1: ds_read B-kk1(4)+A-m0..3-kk1(4)
//   ph2: ds_read A-m4..7-kk0(4); BSTAGE Ba(t+2); vmcnt(6); AWRITE AX(t+1)
//   ph3: ds_read A-m4..7-kk1(4); BSTAGE Bb(t+2)+ALOAD AX(t+2); vmcnt(8);
//        AWRITE AY(t+1)
// FIFO audit (steady): ph2 outstanding {Bb(t+1)2,AX(t+1)4,AY(t+1)4,Ba(t+2)2}
//   -> vmcnt(6) drains AX(t+1). ph3 {AY4,Ba2,Bb2,AX4} -> vmcnt(8) drains AY.
// t=14: ph2 vmcnt(4), ph3 vmcnt(0). Prologue stages B(0),B(1), writes A(0),
// preloads AX(1) -> tile-0 counts match steady state.
__global__ __launch_bounds__(512, 1) void score_8ph_kernel(
    const float* __restrict__ enc, const __bf16* __restrict__ uab,
    const float* __restrict__ hp, const float* __restrict__ va,
    float* __restrict__ e) {
  __shared__ __bf16 As[2][16384];   // 2 x 32 KB
  __shared__ __bf16 Bs[2][16384];   // 2 x 32 KB

  // T1 bijective chunked XCD swizzle: 512 wgs = 8 XCDs x 64
  const int wg = blockIdx.x;
  const int sw = (wg & 7) * 64 + (wg >> 3);
  const int nt = sw & 3;            // N-tile (0..3)
  const int mt = sw >> 2;           // M-tile (0..127)
  const int b  = mt >> 2;           // batch of this 256-row tile

  const int tid  = threadIdx.x;
  const int lane = tid & 63;
  const int wid  = tid >> 6;        // 0..7
  const int wr   = wid >> 2;        // 0..1
  const int wc   = wid & 3;         // 0..3
  const int rl   = lane & 15;
  const int kq   = lane >> 4;
  const int e7   = rl & 7;

  const float* Af = enc + ((size_t)(mt * 256) << 10);
  const __bf16* Bg = uab + ((size_t)(nt * 16) << 14);

  const int aidx = tid >> 3;                        // 0..63
  const int ag8  = ((tid & 7) ^ (aidx & 7)) << 3;   // f32 offset of k-group

  const int s0 = ((kq ^ e7) << 4);
  const int s1 = (((kq + 4) ^ e7) << 4);
  const int arow = (rl + wr * 64) * 128;
  const int brow = (rl + (wc >> 1) * 64) * 128 + (wc & 1) * 16384;

#define LDA(buf, mi, sl) (*(const bf16x8*)((const char*)(buf) + \
    (((mi) >> 2) * 16384 + ((mi) & 3) * 2048) + arow + (sl)))
#define LDB(buf, nj, sl) (*(const bf16x8*)((const char*)(buf) + \
    ((nj) * 2048) + brow + (sl)))

#define BSTAGE(kt2, lp, u) do { \
    const __bf16* _g = Bg + (((size_t)(kt2)) << 14) + (((u) << 10) + tid) * 8; \
    __bf16* _l = (lp) + (((u) << 10) + tid) * 8; \
    async_copy16(_g, _l); \
    async_copy16(_g + 4096, _l + 4096); \
  } while (0)

#define ALOAD(ra, rb, rc, rd, kt2, u) do { \
    const float* _p1 = Af + ((size_t)(aidx + (u) * 64) << 10) + ((kt2) << 6) + ag8; \
    const float* _p2 = _p1 + (128 << 10); \
    ra = *(const f32x4*)_p1; rb = *(const f32x4*)(_p1 + 4); \
    rc = *(const f32x4*)_p2; rd = *(const f32x4*)(_p2 + 4); \
  } while (0)

#define AWRITE(lp, u, ra, rb, rc, rd) do { \
    __bf16* _l = (lp) + ((u) << 13) + tid * 8; \
    bf16x8 o1, o2; \
    o1[0] = (__bf16)ra[0]; o1[1] = (__bf16)ra[1]; \
    o1[2] = (__bf16)ra[2]; o1[3] = (__bf16)ra[3]; \
    o1[4] = (__bf16)rb[0]; o1[5] = (__bf16)rb[1]; \
    o1[6] = (__bf16)rb[2]; o1[7] = (__bf16)rb[3]; \
    o2[0] = (__bf16)rc[0]; o2[1] = (__bf16)rc[1]; \
    o2[2] = (__bf16)rc[2]; o2[3] = (__bf16)rc[3]; \
    o2[4] = (__bf16)rd[0]; o2[5] = (__bf16)rd[1]; \
    o2[6] = (__bf16)rd[2]; o2[7] = (__bf16)rd[3]; \
    *(bf16x8*)_l = o1; \
    *(bf16x8*)(_l + 4096) = o2; \
  } while (0)

#define MFMA16(ml, kkb) do { \
    _Pragma("unroll") \
    for (int nj = 0; nj < 4; ++nj) { \
      acc[(ml) + 0][nj] = __builtin_amdgcn_mfma_f32_16x16x32_bf16(af0, bfr[(kkb) + nj], acc[(ml) + 0][nj], 0, 0, 0); \
      acc[(ml) + 1][nj] = __builtin_amdgcn_mfma_f32_16x16x32_bf16(af1, bfr[(kkb) + nj], acc[(ml) + 1][nj], 0, 0, 0); \
      acc[(ml) + 2][nj] = __builtin_amdgcn_mfma_f32_16x16x32_bf16(af2, bfr[(kkb) + nj], acc[(ml) + 2][nj], 0, 0, 0); \
      acc[(ml) + 3][nj] = __builtin_amdgcn_mfma_f32_16x16x32_bf16(af3, bfr[(kkb) + nj], acc[(ml) + 3][nj], 0, 0, 0); \
    } \
  } while (0)

  f32x4 acc[8][4] = {};
  bf16x8 bfr[8];
  f32x4 xa, xb, xc, xd;   // pending AX regs
  f32x4 ya, yb, yc, yd;   // pending AY regs

  // ---- prologue: B(0), B(1) staged; A(0) written; AX(1) preloaded ----
  BSTAGE(0, &Bs[0][0], 0);
  BSTAGE(0, &Bs[0][0], 1);
  BSTAGE(1, &Bs[1][0], 0);
  BSTAGE(1, &Bs[1][0], 1);
  ALOAD(xa, xb, xc, xd, 0, 0);
  ALOAD(ya, yb, yc, yd, 0, 1);
  asm volatile("s_waitcnt vmcnt(0)" ::: "memory");
  AWRITE(&As[0][0], 0, xa, xb, xc, xd);
  AWRITE(&As[0][0], 1, ya, yb, yc, yd);
  ALOAD(xa, xb, xc, xd, 1, 0);          // AX(1)
  asm volatile("s_waitcnt lgkmcnt(0)" ::: "memory");
  __builtin_amdgcn_s_barrier();

  for (int t = 0; t < 15; ++t) {
    const int p = t & 1;
    const char* Ab = (const char*)&As[p][0];
    const char* Bb = (const char*)&Bs[p][0];
    __bf16* An = &As[p ^ 1][0];

    // ---- phase 0: B kk0 + A m0..3 kk0; issue AY(t+1) ----
    {
#pragma unroll
      for (int nj = 0; nj < 4; ++nj) bfr[nj] = LDB(Bb, nj, s0);
      bf16x8 af0 = LDA(Ab, 0, s0), af1 = LDA(Ab, 1, s0), af2 = LDA(Ab, 2, s0), af3 = LDA(Ab, 3, s0);
      ALOAD(ya, yb, yc, yd, t + 1, 1);
      __builtin_amdgcn_s_barrier();
      asm volatile("s_waitcnt lgkmcnt(0)" ::: "memory");
      __builtin_amdgcn_s_setprio(1);
      MFMA16(0, 0);
      __builtin_amdgcn_s_setprio(0);
      __builtin_amdgcn_s_barrier();
    }
    // ---- phase 1: B kk1 + A m0..3 kk1 ----
    {
#pragma unroll
      for (int nj = 0; nj < 4; ++nj) bfr[4 + nj] = LDB(Bb, nj, s1);
      bf16x8 af0 = LDA(Ab, 0, s1), af1 = LDA(Ab, 1, s1), af2 = LDA(Ab, 2, s1), af3 = LDA(Ab, 3, s1);
      __builtin_amdgcn_s_barrier();
      asm volatile("s_waitcnt lgkmcnt(0)" ::: "memory");
      __builtin_amdgcn_s_setprio(1);
      MFMA16(0, 4);
      __builtin_amdgcn_s_setprio(0);
      __builtin_amdgcn_s_barrier();
    }
    // ---- phase 2: A m4..7 kk0; stage Ba(t+2); publish AX(t+1) ----
    {
      bf16x8 af0 = LDA(Ab, 4, s0), af1 = LDA(Ab, 5, s0), af2 = LDA(Ab, 6, s0), af3 = LDA(Ab, 7, s0);
      if (t < 14) {
        BSTAGE(t + 2, &Bs[p][0], 0);
        asm volatile("s_waitcnt vmcnt(6)" ::: "memory");
      } else {
        asm volatile("s_waitcnt vmcnt(4)" ::: "memory");
      }
      AWRITE(An, 0, xa, xb, xc, xd);    // AX(t+1)
      __builtin_amdgcn_s_barrier();
      asm volatile("s_waitcnt lgkmcnt(0)" ::: "memory");
      __builtin_amdgcn_s_setprio(1);
      MFMA16(4, 0);
      __builtin_amdgcn_s_setprio(0);
      __builtin_amdgcn_s_barrier();
    }
    // ---- phase 3: A m4..7 kk1; stage Bb(t+2)+AX(t+2); publish AY(t+1) ----
    {
      bf16x8 af0 = LDA(Ab, 4, s1), af1 = LDA(Ab, 5, s1), af2 = LDA(Ab, 6, s1), af3 = LDA(Ab, 7, s1);
      if (t < 14) {
        BSTAGE(t + 2, &Bs[p][0], 1);
        ALOAD(xa, xb, xc, xd, t + 2, 0);
        asm volatile("s_waitcnt vmcnt(8)" ::: "memory");
      } else {
        asm volatile("s_waitcnt vmcnt(0)" ::: "memory");
      }
      AWRITE(An, 1, ya, yb, yc, yd);    // AY(t+1)
      __builtin_amdgcn_s_barrier();
      asm volatile("s_waitcnt lgkmcnt(0)" ::: "memory");
      __builtin_amdgcn_s_setprio(1);
      MFMA16(4, 4);
      __builtin_amdgcn_s_setprio(0);
      __builtin_amdgcn_s_barrier();
    }
  }

  // ---- peeled tile 15 (p=1), no staging ----
  {
    const char* Ab = (const char*)&As[1][0];
    const char* Bb = (const char*)&Bs[1][0];
    {
#pragma unroll
      for (int nj = 0; nj < 4; ++nj) bfr[nj] = LDB(Bb, nj, s0);
      bf16x8 af0 = LDA(Ab, 0, s0), af1 = LDA(Ab, 1, s0), af2 = LDA(Ab, 2, s0), af3 = LDA(Ab, 3, s0);
      __builtin_amdgcn_s_barrier();
      asm volatile("s_waitcnt lgkmcnt(0)" ::: "memory");
      __builtin_amdgcn_s_setprio(1);
      MFMA16(0, 0);
      __builtin_amdgcn_s_setprio(0);
      __builtin_amdgcn_s_barrier();
    }
    {
#pragma unroll
      for (int nj = 0; nj < 4; ++nj) bfr[4 + nj] = LDB(Bb, nj, s1);
      bf16x8 af0 = LDA(Ab, 0, s1), af1 = LDA(Ab, 1, s1), af2 = LDA(Ab, 2, s1), af3 = LDA(Ab, 3, s1);
      __builtin_amdgcn_s_barrier();
      asm volatile("s_waitcnt lgkmcnt(0)" ::: "memory");
      __builtin_amdgcn_s_setprio(1);
      MFMA16(0, 4);
      __builtin_amdgcn_s_setprio(0);
      __builtin_amdgcn_s_barrier();
    }
    {
      bf16x8 af0 = LDA(Ab, 4, s0), af1 = LDA(Ab, 5, s0), af2 = LDA(Ab, 6, s0), af3 = LDA(Ab, 7, s0);
      __builtin_amdgcn_s_barrier();
      asm volatile("s_waitcnt lgkmcnt(0)" ::: "memory");
      __builtin_amdgcn_s_setprio(1);
      MFMA16(4, 0);
      __builtin_amdgcn_s_setprio(0);
      __builtin_amdgcn_s_barrier();
    }
    {
      bf16x8 af0 = LDA(Ab, 4, s1), af1 = LDA(Ab, 5, s1), af2 = LDA(Ab, 6, s1), af3 = LDA(Ab, 7, s1);
      __builtin_amdgcn_s_barrier();
      asm volatile("s_waitcnt lgkmcnt(0)" ::: "memory");
      __builtin_amdgcn_s_setprio(1);
      MFMA16(4, 4);
      __builtin_amdgcn_s_setprio(0);
    }
  }

  // ---- epilogue: e[row] += sum_cols tanh(acc + hp)*va ----
  const float* hpb = hp + (b << 10);
#pragma unroll
  for (int mi = 0; mi < 8; ++mi) {
    float rs[4] = {0.f, 0.f, 0.f, 0.f};
#pragma unroll
    for (int nj = 0; nj < 4; ++nj) {
      const int col  = nt * 256 + wc * 64 + nj * 16 + rl;
      const float hv = hpb[col];
      const float vv = va[col];
#pragma unroll
      for (int j = 0; j < 4; ++j)
        rs[j] += fast_tanh(acc[mi][nj][j] + hv) * vv;
    }
#pragma unroll
    for (int j = 0; j < 4; ++j) {
      float r = rs[j];
      r += __shfl_xor(r, 1);
      r += __shfl_xor(r, 2);
      r += __shfl_xor(r, 4);
      r += __shfl_xor(r, 8);
      if (rl == 0)
        atomicAdd(&e[mt * 256 + wr * 128 + mi * 16 + kq * 4 + j], r);
    }
  }
#undef LDA
#undef LDB
#undef BSTAGE
#undef ALOAD
#undef AWRITE
#undef MFMA16
}

// ---------------- K2 (fallback): f32-staged score GEMM -------------------
#define BM 128
#define BN 128
#define BK 32

__device__ __forceinline__ bf16x8 cvt8(const float* p) {
  f32x4 a = *(const f32x4*)p;
  f32x4 b = *(const f32x4*)(p + 4);
  bf16x8 r;
  r[0] = (__bf16)a[0]; r[1] = (__bf16)a[1]; r[2] = (__bf16)a[2]; r[3] = (__bf16)a[3];
  r[4] = (__bf16)b[0]; r[5] = (__bf16)b[1]; r[6] = (__bf16)b[2]; r[7] = (__bf16)b[3];
  return r;
}

__device__ __forceinline__ void score_epilogue(
    f32x4 acc[4][4], int m0, int n0, int b, int lane, int wr, int wc,
    const float* __restrict__ hp, const float* __restrict__ va,
    float* __restrict__ e) {
  const int rl = lane & 15;
  const int rq = lane >> 4;
#pragma unroll
  for (int mi = 0; mi < 4; ++mi) {
    float rs[4] = {0.f, 0.f, 0.f, 0.f};
#pragma unroll
    for (int nj = 0; nj < 4; ++nj) {
      const int col  = n0 + wc * 64 + nj * 16 + rl;
      const float hv = hp[(b << 10) + col];
      const float vv = va[col];
#pragma unroll
      for (int j = 0; j < 4; ++j)
        rs[j] += fast_tanh(acc[mi][nj][j] + hv) * vv;
    }
#pragma unroll
    for (int j = 0; j < 4; ++j) {
      float r = rs[j];
      r += __shfl_xor(r, 1);
      r += __shfl_xor(r, 2);
      r += __shfl_xor(r, 4);
      r += __shfl_xor(r, 8);
      if (rl == 0)
        atomicAdd(&e[m0 + wr * 64 + mi * 16 + rq * 4 + j], r);
    }
  }
}

__global__ __launch_bounds__(256) void score_f32_kernel(
    const float* __restrict__ enc, const float* __restrict__ Ua,
    const float* __restrict__ hp, const float* __restrict__ va,
    float* __restrict__ e) {
  const int m0 = blockIdx.x * BM;
  const int n0 = blockIdx.y * BN;
  const int b  = m0 >> 10;

  __shared__ float As[BM * BK];
  __shared__ float Bs[BN * BK];

  const int tid  = threadIdx.x;
  const int lane = tid & 63;
  const int wid  = tid >> 6;
  const int wr   = wid >> 1;
  const int wc   = wid & 1;

  f32x4 acc[4][4] = {};

  const int srow = tid >> 3;
  const int scol = (tid & 7) * 4;
  const float* gA = enc + (((size_t)(m0 + srow)) << 10) + scol;
  const float* gB = Ua  + (((size_t)(n0 + srow)) << 10) + scol;
  float* lA = As + srow * BK + scol;
  float* lB = Bs + srow * BK + scol;

  for (int kt = 0; kt < HH / BK; ++kt) {
    const int h0 = kt * BK;
    __syncthreads();
#pragma unroll
    for (int i = 0; i < 4; ++i) {
      async_copy16(gA + ((size_t)(i * 32) << 10) + h0, lA + i * 32 * BK);
      async_copy16(gB + ((size_t)(i * 32) << 10) + h0, lB + i * 32 * BK);
    }
    __syncthreads();

    const int koff = (lane >> 4) * 8;
    const int rl   = lane & 15;
    bf16x8 af[4], bfr[4];
#pragma unroll
    for (int mi = 0; mi < 4; ++mi)
      af[mi] = cvt8(As + (wr * 64 + mi * 16 + rl) * BK + koff);
#pragma unroll
    for (int nj = 0; nj < 4; ++nj)
      bfr[nj] = cvt8(Bs + (wc * 64 + nj * 16 + rl) * BK + koff);
#pragma unroll
    for (int mi = 0; mi < 4; ++mi)
#pragma unroll
      for (int nj = 0; nj < 4; ++nj)
        acc[mi][nj] = __builtin_amdgcn_mfma_f32_16x16x32_bf16(
            af[mi], bfr[nj], acc[mi][nj], 0, 0, 0);
  }

  score_epilogue(acc, m0, n0, b, lane, wr, wc, hp, va, e);
}

// ---------------- K3 (fallback): softmax over t per b ---------------------
__global__ __launch_bounds__(256) void softmax_kernel(
    const float* __restrict__ e, const int* __restrict__ mask,
    float* __restrict__ attn) {
  const int b   = blockIdx.x;
  const int tid = threadIdx.x;
  const float* eb = e + (b << 10);
  const int*   mb = mask + (b << 10);
  float v[4];
  float mx = -INFINITY;
#pragma unroll
  for (int j = 0; j < 4; ++j) {
    const int t = tid + j * 256;
    float x = mb[t] ? eb[t] : -INFINITY;
    v[j] = x;
    mx = fmaxf(mx, x);
  }
#pragma unroll
  for (int s = 1; s < 64; s <<= 1) mx = fmaxf(mx, __shfl_xor(mx, s));
  __shared__ float redm[4];
  if ((tid & 63) == 0) redm[tid >> 6] = mx;
  __syncthreads();
  mx = fmaxf(fmaxf(redm[0], redm[1]), fmaxf(redm[2], redm[3]));

  float s = 0.f;
#pragma unroll
  for (int j = 0; j < 4; ++j) { v[j] = __expf(v[j] - mx); s += v[j]; }
#pragma unroll
  for (int st = 1; st < 64; st <<= 1) s += __shfl_xor(s, st);
  __shared__ float reds[4];
  if ((tid & 63) == 0) reds[tid >> 6] = s;
  __syncthreads();
  s = reds[0] + reds[1] + reds[2] + reds[3];
  const float inv = 1.f / s;
#pragma unroll
  for (int j = 0; j < 4; ++j) attn[(b << 10) + tid + j * 256] = v[j] * inv;
}

// ---------------- K4 (fast): fused softmax + context ----------------------
// Block (q 0..7, b): computes block-local softmax of e[b,:] (redundant per q,
// cheap), q==0 writes attn out; then context over h in [q*128, q*128+128).
__global__ __launch_bounds__(256) void context_sm_kernel(
    const float* __restrict__ enc, const float* __restrict__ e,
    const int* __restrict__ mask, float* __restrict__ attn,
    float* __restrict__ ctx) {
  const int q   = blockIdx.x;
  const int b   = blockIdx.y;
  const int tid = threadIdx.x;

  // ---- softmax into at[] ----
  __shared__ float at[1024];
  const float* eb = e + (b << 10);
  const int*   mb = mask + (b << 10);
  float v[4];
  float mx = -INFINITY;
#pragma unroll
  for (int j = 0; j < 4; ++j) {
    const int t = tid + j * 256;
    float x = mb[t] ? eb[t] : -INFINITY;
    v[j] = x;
    mx = fmaxf(mx, x);
  }
#pragma unroll
  for (int s = 1; s < 64; s <<= 1) mx = fmaxf(mx, __shfl_xor(mx, s));
  __shared__ float redm[4];
  if ((tid & 63) == 0) redm[tid >> 6] = mx;
  __syncthreads();
  mx = fmaxf(fmaxf(redm[0], redm[1]), fmaxf(redm[2], redm[3]));
  float s = 0.f;
#pragma unroll
  for (int j = 0; j < 4; ++j) { v[j] = __expf(v[j] - mx); s += v[j]; }
#pragma unroll
  for (int st = 1; st < 64; st <<= 1) s += __shfl_xor(s, st);
  __shared__ float reds[4];
  if ((tid & 63) == 0) reds[tid >> 6] = s;
  __syncthreads();
  s = reds[0] + reds[1] + reds[2] + reds[3];
  const float inv = 1.f / s;
#pragma unroll
  for (int j = 0; j < 4; ++j) {
    const int t = tid + j * 256;
    const float a = v[j] * inv;
    at[t] = a;
    if (q == 0) attn[(b << 10) + t] = a;
  }
  __syncthreads();

  // ---- context: thread (h4 = tid&31, tg = tid>>5), LDS-reduced ----
  const int h4 = tid & 31;
  const int tg = tid >> 5;
  const float* ebase = enc + ((size_t)b << 20) + ((size_t)(tg * 128) << 10)
                       + q * 128 + h4 * 4;
  const float* ap = at + tg * 128;
  f32x4 acc = {0.f, 0.f, 0.f, 0.f};
#pragma unroll 4
  for (int t = 0; t < 128; ++t) {
    f32x4 w4 = *(const f32x4*)(ebase + ((size_t)t << 10));
    const float w = ap[t];
    acc[0] += w * w4[0]; acc[1] += w * w4[1];
    acc[2] += w * w4[2]; acc[3] += w * w4[3];
  }

  __shared__ f32x4 red[8][32];   // 4 KB
  red[tg][h4] = acc;
  __syncthreads();

  if (tid < 32) {
    f32x4 sm = red[0][tid];
#pragma unroll
    for (int r = 1; r < 8; ++r) {
      f32x4 w4 = red[r][tid];
      sm[0] += w4[0]; sm[1] += w4[1]; sm[2] += w4[2]; sm[3] += w4[3];
    }
    *(f32x4*)(ctx + (b << 10) + q * 128 + tid * 4) = sm;
  }
}

// ---------------- K4 (fallback): f32 context, atomic ----------------------
__global__ __launch_bounds__(256) void context_kernel(
    const float* __restrict__ attn, const float* __restrict__ enc,
    float* __restrict__ ctx) {
  const int h  = blockIdx.x * 256 + threadIdx.x;
  const int b  = blockIdx.y;
  const int t0 = blockIdx.z * 128;
  const float* ab = attn + (b << 10) + t0;
  const float* eb = enc + (((size_t)(b << 10) + t0) << 10) + h;
  float acc = 0.f;
#pragma unroll 4
  for (int t = 0; t < 128; ++t)
    acc = fmaf(ab[t], eb[(size_t)t << 10], acc);
  atomicAdd(&ctx[(b << 10) + h], acc);
}

// ---------------- launcher ------------------------------------------------
extern "C" void kernel_launch(void* const* d_in, const int* in_sizes, int n_in,
                              void* d_out, int out_size, void* d_ws, size_t ws_size,
                              hipStream_t stream) {
  const float* h_t  = (const float*)d_in[0];
  const float* enc  = (const float*)d_in[1];
  const int*   mask = (const int*)d_in[2];
  const float* Wa   = (const float*)d_in[3];
  const float* Ua   = (const float*)d_in[4];
  const float* va   = (const float*)d_in[5];

  float* out = (float*)d_out;      // [0,32768): context ; [32768,65536): attn
  float* e   = (float*)d_ws;       // 32768 f32 score accumulator
  float* hp  = e + MM;             // 32768 f32 h_proj

  const size_t base  = 2 * (size_t)MM * sizeof(float);
  const size_t uab_n = (size_t)HH * HH;
  const size_t need  = base + uab_n * sizeof(__bf16);

  if (ws_size >= need) {
    __bf16* uab = (__bf16*)((char*)d_ws + base);
    mini_prep_kernel<<<257, 256, 0, stream>>>(Ua, h_t, Wa, uab, hp, e);
    score_8ph_kernel<<<512, 512, 0, stream>>>(enc, uab, hp, va, e);
    context_sm_kernel<<<dim3(8, BB), 256, 0, stream>>>(
        enc, e, mask, out + BB * HH, out);
  } else {
    hipMemsetAsync(e, 0, MM * sizeof(float), stream);
    hipMemsetAsync(out, 0, BB * HH * sizeof(float), stream);
    hproj_kernel<<<dim3(HH / 128, BB), 128, 0, stream>>>(h_t, Wa, hp);
    score_f32_kernel<<<dim3(MM / BM, HH / BN), 256, 0, stream>>>(enc, Ua, hp, va, e);
    softmax_kernel<<<BB, 256, 0, stream>>>(e, mask, out + BB * HH);
    context_kernel<<<dim3(HH / 256, BB, 8), 256, 0, stream>>>(out + BB * HH, enc, out);
  }
}

// Round 12
// 135.090 us; speedup vs baseline: 1.1891x; 1.1891x over previous
//
#include <hip/hip_runtime.h>

// Problem constants (B=32, T=1024, H=1024)
#define BB 32
#define TT 1024
#define HH 1024
#define MM (BB * TT)   // 32768 rows of the score GEMM

typedef __bf16 bf16x8 __attribute__((ext_vector_type(8)));
typedef float  f32x4  __attribute__((ext_vector_type(4)));

__device__ __forceinline__ void async_copy16(const void* g, void* l) {
  __builtin_amdgcn_global_load_lds(
      (const __attribute__((address_space(1))) void*)g,
      (__attribute__((address_space(3))) void*)l, 16, 0, 0);
}

__device__ __forceinline__ float fast_tanh(float x) {
  float e2 = __expf(2.f * x);                          // v_mul + v_exp
  return 1.f - 2.f * __builtin_amdgcn_rcpf(e2 + 1.f);  // saturates +/-1
}

// ---------------- K0 (mini-prep): hproj + cvt(Ua) + zero(e) ---------------
// Ua cvt keeps the verified chunk layout: chunk R: c=R&2047, t=R>>11,
// kt=t&15, rt=t>>4, u=c>>10, idx=(c>>3)&127, s=c&7, g=s^(idx&7),
// row=(idx&63)+128*((idx>>6)&1)+u*64.
// Blocks [0,128): hproj. [128,256): Ua cvt. Block 256: zero e.
__global__ __launch_bounds__(256) void mini_prep_kernel(
    const float* __restrict__ Ua, const float* __restrict__ h_t,
    const float* __restrict__ Wa, __bf16* __restrict__ uab,
    float* __restrict__ hp, float* __restrict__ e) {
  const int blk = blockIdx.x;
  const int tid = threadIdx.x;

  if (blk < 128) {
    const int b = blk >> 2;
    const int k = (blk & 3) * 256 + tid;
    __shared__ float hs[HH];
    for (int i = tid; i < HH; i += 256) hs[i] = h_t[b * HH + i];
    __syncthreads();
    const float4* w  = (const float4*)(Wa + (size_t)k * HH);
    const float4* hv = (const float4*)hs;
    float acc = 0.f;
#pragma unroll 8
    for (int i = 0; i < HH / 4; ++i) {
      float4 a = w[i];
      float4 h = hv[i];
      acc += a.x * h.x + a.y * h.y + a.z * h.z + a.w * h.w;
    }
    hp[b * HH + k] = acc;
  } else if (blk < 256) {
    int F = (blk - 128) * 256 + tid;
#pragma unroll
    for (int it = 0; it < 4; ++it, F += 32768) {
      const int c   = F & 2047;
      const int t   = F >> 11;
      const int kt  = t & 15;
      const int rt  = t >> 4;
      const int u   = c >> 10;
      const int idx = (c >> 3) & 127;
      const int s   = c & 7;
      const int g   = s ^ (idx & 7);
      const int row = (idx & 63) + ((idx >> 6) & 1) * 128 + u * 64;
      const float* sp = Ua + (((size_t)rt * 256 + row) << 10) + (kt << 6) + (g << 3);
      f32x4 a  = *(const f32x4*)sp;
      f32x4 b2 = *(const f32x4*)(sp + 4);
      bf16x8 o;
      o[0] = (__bf16)a[0];  o[1] = (__bf16)a[1];
      o[2] = (__bf16)a[2];  o[3] = (__bf16)a[3];
      o[4] = (__bf16)b2[0]; o[5] = (__bf16)b2[1];
      o[6] = (__bf16)b2[2]; o[7] = (__bf16)b2[3];
      *(bf16x8*)(uab + (size_t)F * 8) = o;
    }
  } else {
    f32x4 z = {0.f, 0.f, 0.f, 0.f};
    f32x4* ep = (f32x4*)e;
#pragma unroll
    for (int i = 0; i < 32; ++i) ep[i * 256 + tid] = z;
  }
}

// ---------------- K1 (fallback only): standalone hproj --------------------
__global__ __launch_bounds__(128) void hproj_kernel(
    const float* __restrict__ h_t, const float* __restrict__ Wa,
    float* __restrict__ hp) {
  const int k = blockIdx.x * 128 + threadIdx.x;
  const int b = blockIdx.y;
  __shared__ float hs[HH];
  for (int i = threadIdx.x; i < HH; i += 128) hs[i] = h_t[b * HH + i];
  __syncthreads();
  const float4* w  = (const float4*)(Wa + (size_t)k * HH);
  const float4* hv = (const float4*)hs;
  float acc = 0.f;
#pragma unroll 8
  for (int i = 0; i < HH / 4; ++i) {
    float4 a = w[i];
    float4 h = hv[i];
    acc += a.x * h.x + a.y * h.y + a.z * h.z + a.w * h.w;
  }
  hp[b * HH + k] = acc;
}

// ---------------- K2 (fast path): 256^2 8-phase score GEMM, fused A-cvt ---
// R12: reverted to the R10-verified schedule (111 us). A staged from f32 enc
// via reg-load + cvt + swizzled ds_write (T14); all A-publication at the
// tile boundary where pending loads have had ~4 phases of flight time:
//   ph0: ds_read B(8)+A m0..3 kk0(4); ALOAD AY(t+1)
//   ph1: ds_read A m0..3 kk1; BSTAGE Ba(t+2)
//   ph2: ds_read A m4..7 kk0; BSTAGE Bb(t+2)
//   ph3: ds_read A m4..7 kk1; boundary: vmcnt(4) -> AWRITE AX,AY(t+1) ->
//        ALOAD AX(t+2) -> lgkmcnt(0) -> barrier
// vmcnt(4) at boundary leaves Ba/Bb(t+2) gload_lds in flight; t=14 -> 0.
__global__ __launch_bounds__(512, 1) void score_8ph_kernel(
    const float* __restrict__ enc, const __bf16* __restrict__ uab,
    const float* __restrict__ hp, const float* __restrict__ va,
    float* __restrict__ e) {
  __shared__ __bf16 As[2][16384];   // 2 x 32 KB
  __shared__ __bf16 Bs[2][16384];   // 2 x 32 KB

  // T1 bijective chunked XCD swizzle: 512 wgs = 8 XCDs x 64
  const int wg = blockIdx.x;
  const int sw = (wg & 7) * 64 + (wg >> 3);
  const int nt = sw & 3;            // N-tile (0..3)
  const int mt = sw >> 2;           // M-tile (0..127)
  const int b  = mt >> 2;           // batch of this 256-row tile

  const int tid  = threadIdx.x;
  const int lane = tid & 63;
  const int wid  = tid >> 6;        // 0..7
  const int wr   = wid >> 2;        // 0..1
  const int wc   = wid & 3;         // 0..3
  const int rl   = lane & 15;
  const int kq   = lane >> 4;
  const int e7   = rl & 7;

  const float* Af = enc + ((size_t)(mt * 256) << 10);
  const __bf16* Bg = uab + ((size_t)(nt * 16) << 14);

  const int aidx = tid >> 3;                        // 0..63
  const int ag8  = ((tid & 7) ^ (aidx & 7)) << 3;   // f32 offset of k-group

  const int s0 = ((kq ^ e7) << 4);
  const int s1 = (((kq + 4) ^ e7) << 4);
  const int arow = (rl + wr * 64) * 128;
  const int brow = (rl + (wc >> 1) * 64) * 128 + (wc & 1) * 16384;

#define LDA(buf, mi, sl) (*(const bf16x8*)((const char*)(buf) + \
    (((mi) >> 2) * 16384 + ((mi) & 3) * 2048) + arow + (sl)))
#define LDB(buf, nj, sl) (*(const bf16x8*)((const char*)(buf) + \
    ((nj) * 2048) + brow + (sl)))

#define BSTAGE(kt2, lp, u) do { \
    const __bf16* _g = Bg + (((size_t)(kt2)) << 14) + (((u) << 10) + tid) * 8; \
    __bf16* _l = (lp) + (((u) << 10) + tid) * 8; \
    async_copy16(_g, _l); \
    async_copy16(_g + 4096, _l + 4096); \
  } while (0)

#define ALOAD(ra, rb, rc, rd, kt2, u) do { \
    const float* _p1 = Af + ((size_t)(aidx + (u) * 64) << 10) + ((kt2) << 6) + ag8; \
    const float* _p2 = _p1 + (128 << 10); \
    ra = *(const f32x4*)_p1; rb = *(const f32x4*)(_p1 + 4); \
    rc = *(const f32x4*)_p2; rd = *(const f32x4*)(_p2 + 4); \
  } while (0)

#define AWRITE(lp, u, ra, rb, rc, rd) do { \
    __bf16* _l = (lp) + ((u) << 13) + tid * 8; \
    bf16x8 o1, o2; \
    o1[0] = (__bf16)ra[0]; o1[1] = (__bf16)ra[1]; \
    o1[2] = (__bf16)ra[2]; o1[3] = (__bf16)ra[3]; \
    o1[4] = (__bf16)rb[0]; o1[5] = (__bf16)rb[1]; \
    o1[6] = (__bf16)rb[2]; o1[7] = (__bf16)rb[3]; \
    o2[0] = (__bf16)rc[0]; o2[1] = (__bf16)rc[1]; \
    o2[2] = (__bf16)rc[2]; o2[3] = (__bf16)rc[3]; \
    o2[4] = (__bf16)rd[0]; o2[5] = (__bf16)rd[1]; \
    o2[6] = (__bf16)rd[2]; o2[7] = (__bf16)rd[3]; \
    *(bf16x8*)_l = o1; \
    *(bf16x8*)(_l + 4096) = o2; \
  } while (0)

#define MFMA16(ml, kkb) do { \
    _Pragma("unroll") \
    for (int nj = 0; nj < 4; ++nj) { \
      acc[(ml) + 0][nj] = __builtin_amdgcn_mfma_f32_16x16x32_bf16(af0, bfr[(kkb) + nj], acc[(ml) + 0][nj], 0, 0, 0); \
      acc[(ml) + 1][nj] = __builtin_amdgcn_mfma_f32_16x16x32_bf16(af1, bfr[(kkb) + nj], acc[(ml) + 1][nj], 0, 0, 0); \
      acc[(ml) + 2][nj] = __builtin_amdgcn_mfma_f32_16x16x32_bf16(af2, bfr[(kkb) + nj], acc[(ml) + 2][nj], 0, 0, 0); \
      acc[(ml) + 3][nj] = __builtin_amdgcn_mfma_f32_16x16x32_bf16(af3, bfr[(kkb) + nj], acc[(ml) + 3][nj], 0, 0, 0); \
    } \
  } while (0)

  f32x4 acc[8][4] = {};
  bf16x8 bfr[8];
  f32x4 xa, xb, xc, xd;   // pending AX regs
  f32x4 ya, yb, yc, yd;   // pending AY regs

  // ---- prologue ----
  ALOAD(xa, xb, xc, xd, 0, 0);          // AX(0)
  BSTAGE(0, &Bs[0][0], 0);              // Ba(0)
  BSTAGE(0, &Bs[0][0], 1);              // Bb(0)
  ALOAD(ya, yb, yc, yd, 0, 1);          // AY(0)
  BSTAGE(1, &Bs[1][0], 0);              // Ba(1)
  BSTAGE(1, &Bs[1][0], 1);              // Bb(1)
  asm volatile("s_waitcnt vmcnt(4)" ::: "memory");   // A(0)+B(0) landed
  AWRITE(&As[0][0], 0, xa, xb, xc, xd);
  AWRITE(&As[0][0], 1, ya, yb, yc, yd);
  ALOAD(xa, xb, xc, xd, 1, 0);          // AX(1)
  asm volatile("s_waitcnt lgkmcnt(0)" ::: "memory");
  __builtin_amdgcn_s_barrier();

  for (int t = 0; t < 15; ++t) {
    const int p = t & 1;
    const char* Ab = (const char*)&As[p][0];
    const char* Bb = (const char*)&Bs[p][0];
    __bf16* An = &As[p ^ 1][0];

    // ---- phase 0: all B frags + A(kk0, m0..3); issue AY(t+1) loads ----
    {
#pragma unroll
      for (int nj = 0; nj < 4; ++nj) { bfr[nj] = LDB(Bb, nj, s0); bfr[4 + nj] = LDB(Bb, nj, s1); }
      bf16x8 af0 = LDA(Ab, 0, s0), af1 = LDA(Ab, 1, s0), af2 = LDA(Ab, 2, s0), af3 = LDA(Ab, 3, s0);
      ALOAD(ya, yb, yc, yd, t + 1, 1);
      __builtin_amdgcn_s_barrier();
      asm volatile("s_waitcnt lgkmcnt(0)" ::: "memory");
      __builtin_amdgcn_s_setprio(1);
      MFMA16(0, 0);
      __builtin_amdgcn_s_setprio(0);
      __builtin_amdgcn_s_barrier();
    }
    // ---- phase 1: A(kk1, m0..3); stage Ba(t+2) ----
    {
      bf16x8 af0 = LDA(Ab, 0, s1), af1 = LDA(Ab, 1, s1), af2 = LDA(Ab, 2, s1), af3 = LDA(Ab, 3, s1);
      if (t < 14) BSTAGE(t + 2, &Bs[p][0], 0);
      __builtin_amdgcn_s_barrier();
      asm volatile("s_waitcnt lgkmcnt(0)" ::: "memory");
      __builtin_amdgcn_s_setprio(1);
      MFMA16(0, 4);
      __builtin_amdgcn_s_setprio(0);
      __builtin_amdgcn_s_barrier();
    }
    // ---- phase 2: A(kk0, m4..7); stage Bb(t+2) ----
    {
      bf16x8 af0 = LDA(Ab, 4, s0), af1 = LDA(Ab, 5, s0), af2 = LDA(Ab, 6, s0), af3 = LDA(Ab, 7, s0);
      if (t < 14) BSTAGE(t + 2, &Bs[p][0], 1);
      __builtin_amdgcn_s_barrier();
      asm volatile("s_waitcnt lgkmcnt(0)" ::: "memory");
      __builtin_amdgcn_s_setprio(1);
      MFMA16(4, 0);
      __builtin_amdgcn_s_setprio(0);
      __builtin_amdgcn_s_barrier();
    }
    // ---- phase 3: A(kk1, m4..7); boundary: publish A(t+1), load AX(t+2) --
    {
      bf16x8 af0 = LDA(Ab, 4, s1), af1 = LDA(Ab, 5, s1), af2 = LDA(Ab, 6, s1), af3 = LDA(Ab, 7, s1);
      __builtin_amdgcn_s_barrier();
      asm volatile("s_waitcnt lgkmcnt(0)" ::: "memory");
      __builtin_amdgcn_s_setprio(1);
      MFMA16(4, 4);
      __builtin_amdgcn_s_setprio(0);
      if (t < 14) asm volatile("s_waitcnt vmcnt(4)" ::: "memory");
      else        asm volatile("s_waitcnt vmcnt(0)" ::: "memory");
      AWRITE(An, 0, xa, xb, xc, xd);    // AX(t+1)
      AWRITE(An, 1, ya, yb, yc, yd);    // AY(t+1)
      if (t < 14) ALOAD(xa, xb, xc, xd, t + 2, 0);
      asm volatile("s_waitcnt lgkmcnt(0)" ::: "memory");
      __builtin_amdgcn_s_barrier();
    }
  }

  // ---- peeled tile 15 (p=1), no staging ----
  {
    const char* Ab = (const char*)&As[1][0];
    const char* Bb = (const char*)&Bs[1][0];
    {
#pragma unroll
      for (int nj = 0; nj < 4; ++nj) { bfr[nj] = LDB(Bb, nj, s0); bfr[4 + nj] = LDB(Bb, nj, s1); }
      bf16x8 af0 = LDA(Ab, 0, s0), af1 = LDA(Ab, 1, s0), af2 = LDA(Ab, 2, s0), af3 = LDA(Ab, 3, s0);
      __builtin_amdgcn_s_barrier();
      asm volatile("s_waitcnt lgkmcnt(0)" ::: "memory");
      __builtin_amdgcn_s_setprio(1);
      MFMA16(0, 0);
      __builtin_amdgcn_s_setprio(0);
      __builtin_amdgcn_s_barrier();
    }
    {
      bf16x8 af0 = LDA(Ab, 0, s1), af1 = LDA(Ab, 1, s1), af2 = LDA(Ab, 2, s1), af3 = LDA(Ab, 3, s1);
      __builtin_amdgcn_s_barrier();
      asm volatile("s_waitcnt lgkmcnt(0)" ::: "memory");
      __builtin_amdgcn_s_setprio(1);
      MFMA16(0, 4);
      __builtin_amdgcn_s_setprio(0);
      __builtin_amdgcn_s_barrier();
    }
    {
      bf16x8 af0 = LDA(Ab, 4, s0), af1 = LDA(Ab, 5, s0), af2 = LDA(Ab, 6, s0), af3 = LDA(Ab, 7, s0);
      __builtin_amdgcn_s_barrier();
      asm volatile("s_waitcnt lgkmcnt(0)" ::: "memory");
      __builtin_amdgcn_s_setprio(1);
      MFMA16(4, 0);
      __builtin_amdgcn_s_setprio(0);
      __builtin_amdgcn_s_barrier();
    }
    {
      bf16x8 af0 = LDA(Ab, 4, s1), af1 = LDA(Ab, 5, s1), af2 = LDA(Ab, 6, s1), af3 = LDA(Ab, 7, s1);
      __builtin_amdgcn_s_barrier();
      asm volatile("s_waitcnt lgkmcnt(0)" ::: "memory");
      __builtin_amdgcn_s_setprio(1);
      MFMA16(4, 4);
      __builtin_amdgcn_s_setprio(0);
    }
  }

  // ---- epilogue: e[row] += sum_cols tanh(acc + hp)*va ----
  const float* hpb = hp + (b << 10);
#pragma unroll
  for (int mi = 0; mi < 8; ++mi) {
    float rs[4] = {0.f, 0.f, 0.f, 0.f};
#pragma unroll
    for (int nj = 0; nj < 4; ++nj) {
      const int col  = nt * 256 + wc * 64 + nj * 16 + rl;
      const float hv = hpb[col];
      const float vv = va[col];
#pragma unroll
      for (int j = 0; j < 4; ++j)
        rs[j] += fast_tanh(acc[mi][nj][j] + hv) * vv;
    }
#pragma unroll
    for (int j = 0; j < 4; ++j) {
      float r = rs[j];
      r += __shfl_xor(r, 1);
      r += __shfl_xor(r, 2);
      r += __shfl_xor(r, 4);
      r += __shfl_xor(r, 8);
      if (rl == 0)
        atomicAdd(&e[mt * 256 + wr * 128 + mi * 16 + kq * 4 + j], r);
    }
  }
#undef LDA
#undef LDB
#undef BSTAGE
#undef ALOAD
#undef AWRITE
#undef MFMA16
}

// ---------------- K2 (fallback): f32-staged score GEMM -------------------
#define BM 128
#define BN 128
#define BK 32

__device__ __forceinline__ bf16x8 cvt8(const float* p) {
  f32x4 a = *(const f32x4*)p;
  f32x4 b = *(const f32x4*)(p + 4);
  bf16x8 r;
  r[0] = (__bf16)a[0]; r[1] = (__bf16)a[1]; r[2] = (__bf16)a[2]; r[3] = (__bf16)a[3];
  r[4] = (__bf16)b[0]; r[5] = (__bf16)b[1]; r[6] = (__bf16)b[2]; r[7] = (__bf16)b[3];
  return r;
}

__device__ __forceinline__ void score_epilogue(
    f32x4 acc[4][4], int m0, int n0, int b, int lane, int wr, int wc,
    const float* __restrict__ hp, const float* __restrict__ va,
    float* __restrict__ e) {
  const int rl = lane & 15;
  const int rq = lane >> 4;
#pragma unroll
  for (int mi = 0; mi < 4; ++mi) {
    float rs[4] = {0.f, 0.f, 0.f, 0.f};
#pragma unroll
    for (int nj = 0; nj < 4; ++nj) {
      const int col  = n0 + wc * 64 + nj * 16 + rl;
      const float hv = hp[(b << 10) + col];
      const float vv = va[col];
#pragma unroll
      for (int j = 0; j < 4; ++j)
        rs[j] += fast_tanh(acc[mi][nj][j] + hv) * vv;
    }
#pragma unroll
    for (int j = 0; j < 4; ++j) {
      float r = rs[j];
      r += __shfl_xor(r, 1);
      r += __shfl_xor(r, 2);
      r += __shfl_xor(r, 4);
      r += __shfl_xor(r, 8);
      if (rl == 0)
        atomicAdd(&e[m0 + wr * 64 + mi * 16 + rq * 4 + j], r);
    }
  }
}

__global__ __launch_bounds__(256) void score_f32_kernel(
    const float* __restrict__ enc, const float* __restrict__ Ua,
    const float* __restrict__ hp, const float* __restrict__ va,
    float* __restrict__ e) {
  const int m0 = blockIdx.x * BM;
  const int n0 = blockIdx.y * BN;
  const int b  = m0 >> 10;

  __shared__ float As[BM * BK];
  __shared__ float Bs[BN * BK];

  const int tid  = threadIdx.x;
  const int lane = tid & 63;
  const int wid  = tid >> 6;
  const int wr   = wid >> 1;
  const int wc   = wid & 1;

  f32x4 acc[4][4] = {};

  const int srow = tid >> 3;
  const int scol = (tid & 7) * 4;
  const float* gA = enc + (((size_t)(m0 + srow)) << 10) + scol;
  const float* gB = Ua  + (((size_t)(n0 + srow)) << 10) + scol;
  float* lA = As + srow * BK + scol;
  float* lB = Bs + srow * BK + scol;

  for (int kt = 0; kt < HH / BK; ++kt) {
    const int h0 = kt * BK;
    __syncthreads();
#pragma unroll
    for (int i = 0; i < 4; ++i) {
      async_copy16(gA + ((size_t)(i * 32) << 10) + h0, lA + i * 32 * BK);
      async_copy16(gB + ((size_t)(i * 32) << 10) + h0, lB + i * 32 * BK);
    }
    __syncthreads();

    const int koff = (lane >> 4) * 8;
    const int rl   = lane & 15;
    bf16x8 af[4], bfr[4];
#pragma unroll
    for (int mi = 0; mi < 4; ++mi)
      af[mi] = cvt8(As + (wr * 64 + mi * 16 + rl) * BK + koff);
#pragma unroll
    for (int nj = 0; nj < 4; ++nj)
      bfr[nj] = cvt8(Bs + (wc * 64 + nj * 16 + rl) * BK + koff);
#pragma unroll
    for (int mi = 0; mi < 4; ++mi)
#pragma unroll
      for (int nj = 0; nj < 4; ++nj)
        acc[mi][nj] = __builtin_amdgcn_mfma_f32_16x16x32_bf16(
            af[mi], bfr[nj], acc[mi][nj], 0, 0, 0);
  }

  score_epilogue(acc, m0, n0, b, lane, wr, wc, hp, va, e);
}

// ---------------- K3 (fallback): softmax over t per b ---------------------
__global__ __launch_bounds__(256) void softmax_kernel(
    const float* __restrict__ e, const int* __restrict__ mask,
    float* __restrict__ attn) {
  const int b   = blockIdx.x;
  const int tid = threadIdx.x;
  const float* eb = e + (b << 10);
  const int*   mb = mask + (b << 10);
  float v[4];
  float mx = -INFINITY;
#pragma unroll
  for (int j = 0; j < 4; ++j) {
    const int t = tid + j * 256;
    float x = mb[t] ? eb[t] : -INFINITY;
    v[j] = x;
    mx = fmaxf(mx, x);
  }
#pragma unroll
  for (int s = 1; s < 64; s <<= 1) mx = fmaxf(mx, __shfl_xor(mx, s));
  __shared__ float redm[4];
  if ((tid & 63) == 0) redm[tid >> 6] = mx;
  __syncthreads();
  mx = fmaxf(fmaxf(redm[0], redm[1]), fmaxf(redm[2], redm[3]));

  float s = 0.f;
#pragma unroll
  for (int j = 0; j < 4; ++j) { v[j] = __expf(v[j] - mx); s += v[j]; }
#pragma unroll
  for (int st = 1; st < 64; st <<= 1) s += __shfl_xor(s, st);
  __shared__ float reds[4];
  if ((tid & 63) == 0) reds[tid >> 6] = s;
  __syncthreads();
  s = reds[0] + reds[1] + reds[2] + reds[3];
  const float inv = 1.f / s;
#pragma unroll
  for (int j = 0; j < 4; ++j) attn[(b << 10) + tid + j * 256] = v[j] * inv;
}

// ---------------- K4 (fast): fused softmax + context ----------------------
// Block (q 0..7, b): computes block-local softmax of e[b,:] (redundant per q,
// cheap), q==0 writes attn out; then context over h in [q*128, q*128+128).
__global__ __launch_bounds__(256) void context_sm_kernel(
    const float* __restrict__ enc, const float* __restrict__ e,
    const int* __restrict__ mask, float* __restrict__ attn,
    float* __restrict__ ctx) {
  const int q   = blockIdx.x;
  const int b   = blockIdx.y;
  const int tid = threadIdx.x;

  // ---- softmax into at[] ----
  __shared__ float at[1024];
  const float* eb = e + (b << 10);
  const int*   mb = mask + (b << 10);
  float v[4];
  float mx = -INFINITY;
#pragma unroll
  for (int j = 0; j < 4; ++j) {
    const int t = tid + j * 256;
    float x = mb[t] ? eb[t] : -INFINITY;
    v[j] = x;
    mx = fmaxf(mx, x);
  }
#pragma unroll
  for (int s = 1; s < 64; s <<= 1) mx = fmaxf(mx, __shfl_xor(mx, s));
  __shared__ float redm[4];
  if ((tid & 63) == 0) redm[tid >> 6] = mx;
  __syncthreads();
  mx = fmaxf(fmaxf(redm[0], redm[1]), fmaxf(redm[2], redm[3]));
  float s = 0.f;
#pragma unroll
  for (int j = 0; j < 4; ++j) { v[j] = __expf(v[j] - mx); s += v[j]; }
#pragma unroll
  for (int st = 1; st < 64; st <<= 1) s += __shfl_xor(s, st);
  __shared__ float reds[4];
  if ((tid & 63) == 0) reds[tid >> 6] = s;
  __syncthreads();
  s = reds[0] + reds[1] + reds[2] + reds[3];
  const float inv = 1.f / s;
#pragma unroll
  for (int j = 0; j < 4; ++j) {
    const int t = tid + j * 256;
    const float a = v[j] * inv;
    at[t] = a;
    if (q == 0) attn[(b << 10) + t] = a;
  }
  __syncthreads();

  // ---- context: thread (h4 = tid&31, tg = tid>>5), LDS-reduced ----
  const int h4 = tid & 31;
  const int tg = tid >> 5;
  const float* ebase = enc + ((size_t)b << 20) + ((size_t)(tg * 128) << 10)
                       + q * 128 + h4 * 4;
  const float* ap = at + tg * 128;
  f32x4 acc = {0.f, 0.f, 0.f, 0.f};
#pragma unroll 4
  for (int t = 0; t < 128; ++t) {
    f32x4 w4 = *(const f32x4*)(ebase + ((size_t)t << 10));
    const float w = ap[t];
    acc[0] += w * w4[0]; acc[1] += w * w4[1];
    acc[2] += w * w4[2]; acc[3] += w * w4[3];
  }

  __shared__ f32x4 red[8][32];   // 4 KB
  red[tg][h4] = acc;
  __syncthreads();

  if (tid < 32) {
    f32x4 sm = red[0][tid];
#pragma unroll
    for (int r = 1; r < 8; ++r) {
      f32x4 w4 = red[r][tid];
      sm[0] += w4[0]; sm[1] += w4[1]; sm[2] += w4[2]; sm[3] += w4[3];
    }
    *(f32x4*)(ctx + (b << 10) + q * 128 + tid * 4) = sm;
  }
}

// ---------------- K4 (fallback): f32 context, atomic ----------------------
__global__ __launch_bounds__(256) void context_kernel(
    const float* __restrict__ attn, const float* __restrict__ enc,
    float* __restrict__ ctx) {
  const int h  = blockIdx.x * 256 + threadIdx.x;
  const int b  = blockIdx.y;
  const int t0 = blockIdx.z * 128;
  const float* ab = attn + (b << 10) + t0;
  const float* eb = enc + (((size_t)(b << 10) + t0) << 10) + h;
  float acc = 0.f;
#pragma unroll 4
  for (int t = 0; t < 128; ++t)
    acc = fmaf(ab[t], eb[(size_t)t << 10], acc);
  atomicAdd(&ctx[(b << 10) + h], acc);
}

// ---------------- launcher ------------------------------------------------
extern "C" void kernel_launch(void* const* d_in, const int* in_sizes, int n_in,
                              void* d_out, int out_size, void* d_ws, size_t ws_size,
                              hipStream_t stream) {
  const float* h_t  = (const float*)d_in[0];
  const float* enc  = (const float*)d_in[1];
  const int*   mask = (const int*)d_in[2];
  const float* Wa   = (const float*)d_in[3];
  const float* Ua   = (const float*)d_in[4];
  const float* va   = (const float*)d_in[5];

  float* out = (float*)d_out;      // [0,32768): context ; [32768,65536): attn
  float* e   = (float*)d_ws;       // 32768 f32 score accumulator
  float* hp  = e + MM;             // 32768 f32 h_proj

  const size_t base  = 2 * (size_t)MM * sizeof(float);
  const size_t uab_n = (size_t)HH * HH;
  const size_t need  = base + uab_n * sizeof(__bf16);

  if (ws_size >= need) {
    __bf16* uab = (__bf16*)((char*)d_ws + base);
    mini_prep_kernel<<<257, 256, 0, stream>>>(Ua, h_t, Wa, uab, hp, e);
    score_8ph_kernel<<<512, 512, 0, stream>>>(enc, uab, hp, va, e);
    context_sm_kernel<<<dim3(8, BB), 256, 0, stream>>>(
        enc, e, mask, out + BB * HH, out);
  } else {
    hipMemsetAsync(e, 0, MM * sizeof(float), stream);
    hipMemsetAsync(out, 0, BB * HH * sizeof(float), stream);
    hproj_kernel<<<dim3(HH / 128, BB), 128, 0, stream>>>(h_t, Wa, hp);
    score_f32_kernel<<<dim3(MM / BM, HH / BN), 256, 0, stream>>>(enc, Ua, hp, va, e);
    softmax_kernel<<<BB, 256, 0, stream>>>(e, mask, out + BB * HH);
    context_kernel<<<dim3(HH / 256, BB, 8), 256, 0, stream>>>(out + BB * HH, enc, out);
  }
}